// Round 1
// baseline (465.536 us; speedup 1.0000x reference)
//
#include <hip/hip_runtime.h>
#include <hip/hip_bf16.h>
#include <math.h>

// Problem: b=8, c=64, H=W=64, KS=8 -> P = 57*57 = 3249 patch positions.
// Stage 1: per (b,c) Gram of unfold-patches, normalized by its own diagonal
//          (norm over P == sqrt(diag)), sort 64 m-values per column n, pick 9 ranks.
// Stage 2: per b Gram over channels of pooled maps, normalized by its own diagonal,
//          sort 576 p-values per column q, pick 115 ranks.

#define NSHIFT 113  // di=0,dj=0..7 (8)  +  di=1..7, dj=-7..7 (105)

__device__ __forceinline__ void decode_shift(int s, int& di, int& dj) {
    if (s < 8) { di = 0; dj = s; }
    else { int r = s - 8; di = 1 + r / 15; dj = -7 + (r % 15); }
}

// ---------------- Kernel 1: stage-1 per-(b,c) self-correlation ----------------
// grid = 512 (b*c), block = 256
__global__ __launch_bounds__(256) void k1_stage1(const float* __restrict__ x,
                                                 float* __restrict__ xp) {
    __shared__ float img[64 * 65];   // padded rows: stride 65 -> conflict-free column walks
    __shared__ float Wb[4 * 520];    // per-shift row-window sums, s-stride 520 (bank-spread)
    __shared__ float G[64 * 64];     // raw Gram -> corr -> sorted (in place)
    __shared__ float invn[64];

    const int t = threadIdx.x;
    const int bc = blockIdx.x;
    const float* src = x + (size_t)bc * 4096;

    // load 64x64 image into padded LDS (coalesced float4)
    #pragma unroll
    for (int k = 0; k < 4; ++k) {
        int i4 = t + k * 256;                 // float4 index 0..1023
        float4 v = ((const float4*)src)[i4];
        int fl = i4 * 4;
        int row = fl >> 6, col = fl & 63;
        float* d = &img[row * 65 + col];
        d[0] = v.x; d[1] = v.y; d[2] = v.z; d[3] = v.w;
    }
    __syncthreads();

    const int sl = t >> 6, a = t & 63;
    for (int ch = 0; ch < 29; ++ch) {
        // Phase A: per (shift, row a): sliding 57-window sums of product row
        int s = ch * 4 + sl;
        if (s < NSHIFT) {
            int di, dj; decode_shift(s, di, dj);
            if (a + di < 64) {
                int adj = dj < 0 ? -dj : dj;
                int kjlo = dj < 0 ? -dj : 0;
                int nkj = 8 - adj;
                const float* r0 = &img[a * 65 + kjlo];
                const float* r1 = &img[(a + di) * 65 + kjlo + dj];
                float w = 0.f;
                #pragma unroll
                for (int bb = 0; bb < 57; ++bb) w = fmaf(r0[bb], r1[bb], w);
                float* wrow = &Wb[sl * 520 + a * 8 + kjlo];
                wrow[0] = w;
                for (int st = 1; st < nkj; ++st) {
                    w += r0[56 + st] * r1[56 + st] - r0[st - 1] * r1[st - 1];
                    wrow[st] = w;
                }
            }
        }
        __syncthreads();
        // Phase B: per (shift, kj): sliding 57-window over rows -> G entries (+ mirror)
        if (t < 32) {
            int sl2 = t >> 3, kjl = t & 7;
            int s2 = ch * 4 + sl2;
            if (s2 < NSHIFT) {
                int di, dj; decode_shift(s2, di, dj);
                int adj = dj < 0 ? -dj : dj;
                int kjlo = dj < 0 ? -dj : 0;
                int nkj = 8 - adj;
                if (kjl < nkj) {
                    int kj = kjlo + kjl;
                    const float* wp = &Wb[sl2 * 520 + kj];
                    float w = 0.f;
                    #pragma unroll
                    for (int aa = 0; aa < 57; ++aa) w += wp[aa * 8];
                    int nki = 8 - di;   // di >= 0 in our shift set
                    for (int ki = 0; ki < nki; ++ki) {
                        if (ki > 0) w += wp[(ki + 56) * 8] - wp[(ki - 1) * 8];
                        int m = ki * 8 + kj;
                        int n = (ki + di) * 8 + (kj + dj);
                        G[m * 64 + n] = w;
                        G[n * 64 + m] = w;
                    }
                }
            }
        }
        __syncthreads();
    }

    // normalize: corr[m,n] = G[m,n] / (max(sqrt(G[m,m]),eps)*max(sqrt(G[n,n]),eps)*P)
    if (t < 64) invn[t] = 1.0f / fmaxf(sqrtf(G[t * 64 + t]), 1e-12f);
    __syncthreads();
    const float sc = 1.0f / 3249.0f;
    for (int i = t; i < 4096; i += 256) {
        int m = i >> 6, n = i & 63;
        G[i] *= invn[m] * invn[n] * sc;
    }
    __syncthreads();

    // bitonic sort each column n DESCENDING over m (64 elems, 21 passes)
    for (int k = 2; k <= 64; k <<= 1) {
        for (int j = k >> 1; j > 0; j >>= 1) {
            #pragma unroll
            for (int rep = 0; rep < 8; ++rep) {
                int tsk = rep * 256 + t;        // 2048 disjoint pairs
                int n = tsk & 63;
                int pr = tsk >> 6;
                int i = ((pr & ~(j - 1)) << 1) | (pr & (j - 1));
                int l = i | j;
                float av = G[i * 64 + n], bv = G[l * 64 + n];
                bool sw = ((i & k) == 0) ? (av < bv) : (av > bv);
                if (sw) { G[i * 64 + n] = bv; G[l * 64 + n] = av; }
            }
            __syncthreads();
        }
    }

    // ranks2 = round(linspace(1,63,9)) with numpy half-to-even: {1,9,16,24,32,40,48,55,63}
    const int ranks2[9] = {1, 9, 16, 24, 32, 40, 48, 55, 63};
    for (int i = t; i < 576; i += 256) {
        int r = i >> 6, n = i & 63;
        xp[(size_t)bc * 576 + i] = G[ranks2[r] * 64 + n];
    }
}

// ---------------- Kernel 2: stage-2 channel norms ----------------
// grid = 8, block = 576
__global__ __launch_bounds__(576) void k2_norms(const float* __restrict__ xp,
                                                float* __restrict__ inv2) {
    int b = blockIdx.x, p = threadIdx.x;
    const float* base = xp + (size_t)b * 64 * 576 + p;
    float s = 0.f;
    #pragma unroll
    for (int c = 0; c < 64; ++c) { float v = base[c * 576]; s = fmaf(v, v, s); }
    inv2[b * 576 + p] = 1.0f / fmaxf(sqrtf(s), 1e-12f);
}

// ---------------- Kernel 3: stage-2 corr columns + sort + ranks ----------------
// grid = 8*144 (4 q-columns per block), block = 256
__global__ __launch_bounds__(256) void k3_stage2(const float* __restrict__ xp,
                                                 const float* __restrict__ inv2,
                                                 float* __restrict__ out) {
    __shared__ float xq[4 * 64];
    __shared__ float sbuf[4 * 1032];   // row stride 1032 -> 8-bank offset per column
    int t = threadIdx.x;
    int b = blockIdx.x / 144;
    int qg = blockIdx.x % 144;
    int q0 = qg * 4;
    const float* xpb = xp + (size_t)b * 64 * 576;

    { int qq = t >> 6, c = t & 63;
      xq[qq * 64 + c] = xpb[c * 576 + q0 + qq]; }
    __syncthreads();

    float iq0 = inv2[b * 576 + q0 + 0];
    float iq1 = inv2[b * 576 + q0 + 1];
    float iq2 = inv2[b * 576 + q0 + 2];
    float iq3 = inv2[b * 576 + q0 + 3];

    for (int p = t; p < 576; p += 256) {
        float s0 = 0.f, s1 = 0.f, s2 = 0.f, s3 = 0.f;
        #pragma unroll
        for (int c = 0; c < 64; ++c) {
            float xv = xpb[c * 576 + p];          // coalesced across lanes
            s0 = fmaf(xv, xq[c],       s0);       // LDS broadcast
            s1 = fmaf(xv, xq[64 + c],  s1);
            s2 = fmaf(xv, xq[128 + c], s2);
            s3 = fmaf(xv, xq[192 + c], s3);
        }
        float ip = inv2[b * 576 + p] * 0.015625f;   // /64
        sbuf[0 * 1032 + p] = s0 * ip * iq0;
        sbuf[1 * 1032 + p] = s1 * ip * iq1;
        sbuf[2 * 1032 + p] = s2 * ip * iq2;
        sbuf[3 * 1032 + p] = s3 * ip * iq3;
    }
    #pragma unroll
    for (int qq = 0; qq < 4; ++qq)
        for (int p = 576 + t; p < 1024; p += 256)
            sbuf[qq * 1032 + p] = -3.4e38f;        // pads sink to the tail (descending)
    __syncthreads();

    // bitonic sort each of the 4 columns DESCENDING (N=1024, 55 passes)
    for (int k = 2; k <= 1024; k <<= 1) {
        for (int j = k >> 1; j > 0; j >>= 1) {
            #pragma unroll
            for (int rep = 0; rep < 8; ++rep) {
                int tsk = rep * 256 + t;           // 2048 disjoint pairs (4 cols x 512)
                int qq = tsk & 3, pr = tsk >> 2;
                int i = ((pr & ~(j - 1)) << 1) | (pr & (j - 1));
                int l = i | j;
                float* sb = &sbuf[qq * 1032];
                float av = sb[i], bv = sb[l];
                bool sw = ((i & k) == 0) ? (av < bv) : (av > bv);
                if (sw) { sb[i] = bv; sb[l] = av; }
            }
            __syncthreads();
        }
    }

    // ranks = round(linspace(1,575,115)); exact integer form:
    //   r_i = 1 + 5i + floor(2i/57) + (2i mod 57 >= 29)   (never an exact .5 -> safe)
    for (int i = t; i < 460; i += 256) {
        int qq = i / 115, rr = i % 115;
        int ti = 2 * rr;
        int rank = 1 + 5 * rr + ti / 57 + ((ti % 57) >= 29 ? 1 : 0);
        out[(size_t)b * 115 * 576 + rr * 576 + q0 + qq] = sbuf[qq * 1032 + rank];
    }
}

extern "C" void kernel_launch(void* const* d_in, const int* in_sizes, int n_in,
                              void* d_out, int out_size, void* d_ws, size_t ws_size,
                              hipStream_t stream) {
    const float* x = (const float*)d_in[0];   // [8,64,64,64] fp32
    float* out = (float*)d_out;               // [8,115,24,24] fp32
    float* xp   = (float*)d_ws;               // [8,64,576] pooled stage-1 values
    float* inv2 = xp + 8 * 64 * 576;          // [8,576] stage-2 inverse channel norms

    k1_stage1<<<dim3(512),  dim3(256), 0, stream>>>(x, xp);
    k2_norms <<<dim3(8),    dim3(576), 0, stream>>>(xp, inv2);
    k3_stage2<<<dim3(1152), dim3(256), 0, stream>>>(xp, inv2, out);
}

// Round 2
// 277.107 us; speedup vs baseline: 1.6800x; 1.6800x over previous
//
#include <hip/hip_runtime.h>
#include <hip/hip_bf16.h>
#include <math.h>

// b=8, c=64, H=W=64, KS=8 -> P = 57*57 = 3249.
// Stage 1 per (b,c): Gram of unfold-patches normalized by its own diagonal
//   (norm over P == sqrt(diag)); sort 64 m per column n desc; 9 ranks.
// Stage 2 per b: channel Gram of pooled maps normalized by its own diagonal;
//   sort 576 p per column q desc; 115 ranks.

#define NSHIFT 113  // di=0,dj=0..7 (8)  +  di=1..7, dj=-7..7 (105)
#define CH 8        // shifts per chunk in k1
#define NCH 15      // ceil(113/8)

__device__ __forceinline__ void decode_shift(int s, int& di, int& dj) {
    if (s < 8) { di = 0; dj = s; }
    else { int r = s - 8; di = 1 + r / 15; dj = -7 + (r % 15); }
}

// ---------------- Kernel 1: stage-1 per-(b,c) self-correlation ----------------
// grid = 512 (b*c), block = 256
__global__ __launch_bounds__(256) void k1_stage1(const float* __restrict__ x,
                                                 float* __restrict__ xp) {
    __shared__ float img[64 * 65];   // padded rows: conflict-free column walks
    __shared__ float Wb[CH * 520];   // per-shift row-window sums
    __shared__ float G[64 * 64];     // raw Gram -> corr -> sorted (in place)
    __shared__ float invn[64];

    const int t = threadIdx.x;
    const int bc = blockIdx.x;
    const float* src = x + (size_t)bc * 4096;

    #pragma unroll
    for (int k = 0; k < 4; ++k) {
        int i4 = t + k * 256;
        float4 v = ((const float4*)src)[i4];
        int fl = i4 * 4;
        int row = fl >> 6, col = fl & 63;
        float* d = &img[row * 65 + col];
        d[0] = v.x; d[1] = v.y; d[2] = v.z; d[3] = v.w;
    }
    __syncthreads();

    for (int ch = 0; ch < NCH; ++ch) {
        // Phase A: per (shift, row a): sliding 57-window sums of product row
        #pragma unroll
        for (int it = 0; it < 2; ++it) {
            int task = it * 256 + t;          // 0..511 = 8 shifts x 64 rows
            int sl = task >> 6, a = task & 63;
            int s = ch * CH + sl;
            if (s < NSHIFT) {
                int di, dj; decode_shift(s, di, dj);
                if (a + di < 64) {
                    int adj = dj < 0 ? -dj : dj;
                    int kjlo = dj < 0 ? -dj : 0;
                    int nkj = 8 - adj;
                    const float* r0 = &img[a * 65 + kjlo];
                    const float* r1 = &img[(a + di) * 65 + kjlo + dj];
                    float w = 0.f;
                    #pragma unroll
                    for (int bb = 0; bb < 57; ++bb) w = fmaf(r0[bb], r1[bb], w);
                    float* wrow = &Wb[sl * 520 + a * 8 + kjlo];
                    wrow[0] = w;
                    for (int st = 1; st < nkj; ++st) {
                        w += r0[56 + st] * r1[56 + st] - r0[st - 1] * r1[st - 1];
                        wrow[st] = w;
                    }
                }
            }
        }
        __syncthreads();
        // Phase B: per (shift, kj): sliding 57-window over rows -> G (+ mirror)
        if (t < CH * 8) {
            int sl2 = t >> 3, kjl = t & 7;
            int s2 = ch * CH + sl2;
            if (s2 < NSHIFT) {
                int di, dj; decode_shift(s2, di, dj);
                int adj = dj < 0 ? -dj : dj;
                int kjlo = dj < 0 ? -dj : 0;
                int nkj = 8 - adj;
                if (kjl < nkj) {
                    int kj = kjlo + kjl;
                    const float* wp = &Wb[sl2 * 520 + kj];
                    float w = 0.f;
                    #pragma unroll
                    for (int aa = 0; aa < 57; ++aa) w += wp[aa * 8];
                    int nki = 8 - di;   // di >= 0
                    for (int ki = 0; ki < nki; ++ki) {
                        if (ki > 0) w += wp[(ki + 56) * 8] - wp[(ki - 1) * 8];
                        int m = ki * 8 + kj;
                        int n = (ki + di) * 8 + (kj + dj);
                        G[m * 64 + n] = w;
                        G[n * 64 + m] = w;
                    }
                }
            }
        }
        __syncthreads();
    }

    // corr[m,n] = G[m,n] / (max(sqrt(G[m,m]),eps)*max(sqrt(G[n,n]),eps)*P)
    if (t < 64) invn[t] = 1.0f / fmaxf(sqrtf(G[t * 64 + t]), 1e-12f);
    __syncthreads();
    const float sc = 1.0f / 3249.0f;
    for (int i = t; i < 4096; i += 256) {
        int m = i >> 6, n = i & 63;
        G[i] *= invn[m] * invn[n] * sc;
    }
    __syncthreads();

    // bitonic sort each column n DESCENDING over m (64 elems)
    for (int k = 2; k <= 64; k <<= 1) {
        for (int j = k >> 1; j > 0; j >>= 1) {
            #pragma unroll
            for (int rep = 0; rep < 8; ++rep) {
                int tsk = rep * 256 + t;        // 2048 disjoint pairs
                int n = tsk & 63;
                int pr = tsk >> 6;
                int i = ((pr & ~(j - 1)) << 1) | (pr & (j - 1));
                int l = i | j;
                float av = G[i * 64 + n], bv = G[l * 64 + n];
                bool sw = ((i & k) == 0) ? (av < bv) : (av > bv);
                if (sw) { G[i * 64 + n] = bv; G[l * 64 + n] = av; }
            }
            __syncthreads();
        }
    }

    // ranks2 = round(linspace(1,63,9)) half-to-even: {1,9,16,24,32,40,48,55,63}
    const int ranks2[9] = {1, 9, 16, 24, 32, 40, 48, 55, 63};
    for (int i = t; i < 576; i += 256) {
        int r = i >> 6, n = i & 63;
        xp[(size_t)bc * 576 + i] = G[ranks2[r] * 64 + n];
    }
}

// ---------------- Kernel 2: stage-2 channel norms ----------------
// grid = 8, block = 576
__global__ __launch_bounds__(576) void k2_norms(const float* __restrict__ xp,
                                                float* __restrict__ inv2) {
    int b = blockIdx.x, p = threadIdx.x;
    const float* base = xp + (size_t)b * 64 * 576 + p;
    float s = 0.f;
    #pragma unroll
    for (int c = 0; c < 64; ++c) { float v = base[c * 576]; s = fmaf(v, v, s); }
    inv2[b * 576 + p] = 1.0f / fmaxf(sqrtf(s), 1e-12f);
}

// ---------------- Kernel 3: stage-2 corr columns + REGISTER bitonic sort ----------------
// grid = 8*144 (4 q-columns per block, one column per wave), block = 256
__global__ __launch_bounds__(256) void k3_stage2(const float* __restrict__ xp,
                                                 const float* __restrict__ inv2,
                                                 float* __restrict__ out) {
    __shared__ float xq[4 * 64];
    __shared__ float sbuf[4][1032];
    int t = threadIdx.x;
    int b = blockIdx.x / 144;
    int qg = blockIdx.x % 144;
    int q0 = qg * 4;
    const float* xpb = xp + (size_t)b * 64 * 576;

    { int qq = t >> 6, c = t & 63;
      xq[qq * 64 + c] = xpb[c * 576 + q0 + qq]; }
    __syncthreads();

    float iq0 = inv2[b * 576 + q0 + 0];
    float iq1 = inv2[b * 576 + q0 + 1];
    float iq2 = inv2[b * 576 + q0 + 2];
    float iq3 = inv2[b * 576 + q0 + 3];

    for (int p = t; p < 576; p += 256) {
        float s0 = 0.f, s1 = 0.f, s2 = 0.f, s3 = 0.f;
        #pragma unroll
        for (int c = 0; c < 64; ++c) {
            float xv = xpb[c * 576 + p];          // coalesced across lanes
            s0 = fmaf(xv, xq[c],       s0);       // LDS broadcast
            s1 = fmaf(xv, xq[64 + c],  s1);
            s2 = fmaf(xv, xq[128 + c], s2);
            s3 = fmaf(xv, xq[192 + c], s3);
        }
        float ip = inv2[b * 576 + p] * 0.015625f;   // /64
        sbuf[0][p] = s0 * ip * iq0;
        sbuf[1][p] = s1 * ip * iq1;
        sbuf[2][p] = s2 * ip * iq2;
        sbuf[3][p] = s3 * ip * iq3;
    }
    #pragma unroll
    for (int qq = 0; qq < 4; ++qq)
        for (int p = 576 + t; p < 1024; p += 256)
            sbuf[qq][p] = -3.4e38f;              // pads sink to tail (descending)
    __syncthreads();

    // --- per-wave register bitonic sort of 1024 elems, idx = lane*16 + r ---
    const int wv = t >> 6, lane = t & 63;
    float* sb = sbuf[wv];
    float v[16];
    #pragma unroll
    for (int r = 0; r < 16; ++r) v[r] = sb[lane * 16 + r];

    #pragma unroll
    for (int kk = 2; kk <= 1024; kk <<= 1) {
        #pragma unroll
        for (int j = kk >> 1; j > 0; j >>= 1) {
            if (j >= 16) {
                // cross-lane: partner lane = lane ^ (j>>4); kk>=32 so dir bit is a lane bit
                int jl = j >> 4;
                bool upper = (lane & jl) != 0;
                bool dir0  = (lane & (kk >> 4)) == 0;
                bool keep_max = dir0 ^ upper;
                #pragma unroll
                for (int r = 0; r < 16; ++r) {
                    float o = __shfl_xor(v[r], jl, 64);
                    v[r] = keep_max ? fmaxf(v[r], o) : fminf(v[r], o);
                }
            } else {
                // in-register: pairs (ra, ra|j) within the lane
                #pragma unroll
                for (int ra = 0; ra < 16; ++ra) {
                    if ((ra & j) == 0) {
                        int rb = ra | j;
                        bool dir0 = (kk >= 16) ? ((lane & (kk >> 4)) == 0)
                                               : ((ra & kk) == 0);
                        float a = v[ra], bb = v[rb];
                        float mx = fmaxf(a, bb), mn = fminf(a, bb);
                        v[ra] = dir0 ? mx : mn;
                        v[rb] = dir0 ? mn : mx;
                    }
                }
            }
        }
    }

    #pragma unroll
    for (int r = 0; r < 16; ++r) sb[lane * 16 + r] = v[r];
    __syncthreads();

    // ranks = round(linspace(1,575,115)) == 1 + 5i + floor(2i/57) + (2i%57>=29)
    if (t < 115) {
        int ti = 2 * t;
        int rank = 1 + 5 * t + ti / 57 + ((ti % 57) >= 29 ? 1 : 0);
        float4 o = make_float4(sbuf[0][rank], sbuf[1][rank], sbuf[2][rank], sbuf[3][rank]);
        *(float4*)&out[(size_t)b * 115 * 576 + (size_t)t * 576 + q0] = o;
    }
}

extern "C" void kernel_launch(void* const* d_in, const int* in_sizes, int n_in,
                              void* d_out, int out_size, void* d_ws, size_t ws_size,
                              hipStream_t stream) {
    const float* x = (const float*)d_in[0];   // [8,64,64,64] fp32
    float* out = (float*)d_out;               // [8,115,24,24] fp32
    float* xp   = (float*)d_ws;               // [8,64,576]
    float* inv2 = xp + 8 * 64 * 576;          // [8,576]

    k1_stage1<<<dim3(512),  dim3(256), 0, stream>>>(x, xp);
    k2_norms <<<dim3(8),    dim3(576), 0, stream>>>(xp, inv2);
    k3_stage2<<<dim3(1152), dim3(256), 0, stream>>>(xp, inv2, out);
}